// Round 1
// baseline (27973.459 us; speedup 1.0000x reference)
//
#include <hip/hip_runtime.h>
#include <cstdint>
#include <cstddef>

#define NNODES 100000
#define FIN    512
#define HID    256
#define NCLS   64
#define KSTEPS 10
#define ALPHA  0.1f

// ---------------- Tiled f32 GEMM: C = act(A @ B + bias) ----------------
// A: [M,K] row-major, B: [K,N] row-major, C: [M,N]. N, K multiples of 64/16.
template<bool RELU>
__global__ __launch_bounds__(256)
void gemm_bias(const float* __restrict__ A, const float* __restrict__ B,
               const float* __restrict__ bias, float* __restrict__ C,
               int M, int K, int N) {
  __shared__ float As[16][68];   // [k][m], stride 68 keeps float4 alignment
  __shared__ float Bs[16][68];   // [k][n]
  const int tid = threadIdx.x;
  const int tx = tid & 15;        // 16 col-threads
  const int ty = tid >> 4;        // 16 row-threads
  const int row0 = blockIdx.y * 64;
  const int col0 = blockIdx.x * 64;

  float acc[4][4] = {};

  for (int k0 = 0; k0 < K; k0 += 16) {
    // Load A tile 64x16 (1024 elems, 4 per thread)
#pragma unroll
    for (int i = 0; i < 4; ++i) {
      int idx = tid + i * 256;
      int r = idx >> 4;     // 0..63 (m)
      int c = idx & 15;     // 0..15 (k)
      int gr = row0 + r;
      As[c][r] = (gr < M) ? A[(size_t)gr * K + (k0 + c)] : 0.f;
    }
    // Load B tile 16x64 (coalesced over n)
#pragma unroll
    for (int i = 0; i < 4; ++i) {
      int idx = tid + i * 256;
      int rk = idx >> 6;    // 0..15 (k)
      int cn = idx & 63;    // 0..63 (n)
      Bs[rk][cn] = B[(size_t)(k0 + rk) * N + (col0 + cn)];
    }
    __syncthreads();
#pragma unroll
    for (int kk = 0; kk < 16; ++kk) {
      const float4 av = *(const float4*)&As[kk][ty * 4];
      const float4 bv = *(const float4*)&Bs[kk][tx * 4];
      const float a4[4] = {av.x, av.y, av.z, av.w};
      const float b4[4] = {bv.x, bv.y, bv.z, bv.w};
#pragma unroll
      for (int i = 0; i < 4; ++i)
#pragma unroll
        for (int j = 0; j < 4; ++j)
          acc[i][j] = fmaf(a4[i], b4[j], acc[i][j]);
    }
    __syncthreads();
  }

  const int gc = col0 + tx * 4;
  const float4 bv = *(const float4*)&bias[gc];
#pragma unroll
  for (int i = 0; i < 4; ++i) {
    int gr = row0 + ty * 4 + i;
    if (gr < M) {
      float4 v;
      v.x = acc[i][0] + bv.x;
      v.y = acc[i][1] + bv.y;
      v.z = acc[i][2] + bv.z;
      v.w = acc[i][3] + bv.w;
      if (RELU) {
        v.x = fmaxf(v.x, 0.f); v.y = fmaxf(v.y, 0.f);
        v.z = fmaxf(v.z, 0.f); v.w = fmaxf(v.w, 0.f);
      }
      *(float4*)&C[(size_t)gr * N + gc] = v;
    }
  }
}

// ---------------- degree / norm ----------------
__global__ void count_deg(const int* __restrict__ dst, unsigned* __restrict__ deg, int E) {
  int e = blockIdx.x * 256 + threadIdx.x;
  if (e < E) atomicAdd(&deg[dst[e]], 1u);
}

__global__ void make_norm(float* __restrict__ norm, int n) {
  int i = blockIdx.x * 256 + threadIdx.x;
  if (i < n) {
    unsigned c = ((const unsigned*)norm)[i];
    norm[i] = rsqrtf((float)(c + 1u));   // +1 for self-loop
  }
}

// ---------------- propagation ----------------
// 16 threads per edge, 4 channels (float4) each.
__global__ __launch_bounds__(256)
void prop_edges(const float* __restrict__ h, const float* __restrict__ norm,
                const int* __restrict__ src, const int* __restrict__ dst,
                float* __restrict__ agg, int E) {
  long long t = (long long)blockIdx.x * 256 + threadIdx.x;
  int e = (int)(t >> 4);
  if (e >= E) return;
  int c = (int)(t & 15) << 2;
  int s = src[e];
  int d = dst[e];
  float ns = norm[s];
  const float4 hv = *(const float4*)&h[(size_t)s * NCLS + c];
  float* outp = &agg[(size_t)d * NCLS + c];
  unsafeAtomicAdd(outp + 0, hv.x * ns);
  unsafeAtomicAdd(outp + 1, hv.y * ns);
  unsafeAtomicAdd(outp + 2, hv.z * ns);
  unsafeAtomicAdd(outp + 3, hv.w * ns);
}

// h_new = (1-a)*norm*(agg + norm*h_cur) + a*h0   (self-loop folded in)
__global__ __launch_bounds__(256)
void prop_finalize(float* __restrict__ h_new, const float* __restrict__ h_cur,
                   const float* __restrict__ norm, const float* __restrict__ h0,
                   int total) {
  int i = blockIdx.x * 256 + threadIdx.x;
  if (i >= total) return;
  int row = i >> 6;   // / NCLS
  float n = norm[row];
  float aggv = h_new[i] + n * h_cur[i];
  h_new[i] = (1.0f - ALPHA) * n * aggv + ALPHA * h0[i];
}

// ---------------- log_softmax (one wave per row, C = 64 = wave width) ----------------
__global__ __launch_bounds__(256)
void log_softmax_k(const float* __restrict__ h, float* __restrict__ out, int n) {
  int wave = threadIdx.x >> 6;
  int lane = threadIdx.x & 63;
  int row = blockIdx.x * 4 + wave;
  if (row >= n) return;
  float x = h[(size_t)row * NCLS + lane];
  float m = x;
#pragma unroll
  for (int o = 32; o; o >>= 1) m = fmaxf(m, __shfl_xor(m, o, 64));
  float ex = expf(x - m);
  float s = ex;
#pragma unroll
  for (int o = 32; o; o >>= 1) s += __shfl_xor(s, o, 64);
  out[(size_t)row * NCLS + lane] = x - m - logf(s);
}

// ---------------- launch ----------------
extern "C" void kernel_launch(void* const* d_in, const int* in_sizes, int n_in,
                              void* d_out, int out_size, void* d_ws, size_t ws_size,
                              hipStream_t stream) {
  (void)n_in; (void)out_size; (void)ws_size;
  const float* feat = (const float*)d_in[0];
  const float* w1   = (const float*)d_in[1];
  const float* b1   = (const float*)d_in[2];
  const float* w2   = (const float*)d_in[3];
  const float* b2   = (const float*)d_in[4];
  const int*   src  = (const int*)d_in[5];
  const int*   dst  = (const int*)d_in[6];
  const int E = in_sizes[5];
  float* out = (float*)d_out;

  // workspace layout
  char* ws = (char*)d_ws;
  size_t off = 0;
  float* norm = (float*)(ws + off);
  off += ((size_t)NNODES * 4 + 255) & ~(size_t)255;
  float* h0 = (float*)(ws + off);
  off += (size_t)NNODES * NCLS * 4;
  float* h1 = (float*)(ws + off);                 // N*HID floats (used only by MLP)
  float* pb0 = h1;                                // ping-pong buffers alias h1 region
  float* pb1 = (float*)((char*)h1 + (size_t)NNODES * NCLS * 4);

  // ---- degree / norm ----
  hipMemsetAsync(norm, 0, (size_t)NNODES * 4, stream);
  count_deg<<<(E + 255) / 256, 256, 0, stream>>>(dst, (unsigned*)norm, E);
  make_norm<<<(NNODES + 255) / 256, 256, 0, stream>>>(norm, NNODES);

  // ---- MLP encoder ----
  dim3 g1(HID / 64, (NNODES + 63) / 64);
  gemm_bias<true><<<g1, 256, 0, stream>>>(feat, w1, b1, h1, NNODES, FIN, HID);
  dim3 g2(NCLS / 64, (NNODES + 63) / 64);
  gemm_bias<false><<<g2, 256, 0, stream>>>(h1, w2, b2, h0, NNODES, HID, NCLS);

  // ---- APPNP propagation ----
  const float* cur = h0;
  float* bufs[2] = {pb0, pb1};
  const size_t hbytes = (size_t)NNODES * NCLS * 4;
  const long long ethreads = (long long)E * 16;
  for (int k = 0; k < KSTEPS; ++k) {
    float* nxt = bufs[k & 1];
    hipMemsetAsync(nxt, 0, hbytes, stream);
    prop_edges<<<(int)((ethreads + 255) / 256), 256, 0, stream>>>(cur, norm, src, dst, nxt, E);
    prop_finalize<<<(NNODES * NCLS + 255) / 256, 256, 0, stream>>>(nxt, cur, norm, h0, NNODES * NCLS);
    cur = nxt;
  }

  // ---- log_softmax ----
  log_softmax_k<<<(NNODES + 3) / 4, 256, 0, stream>>>(cur, out, NNODES);
}

// Round 2
// 2247.634 us; speedup vs baseline: 12.4457x; 12.4457x over previous
//
#include <hip/hip_runtime.h>
#include <cstdint>
#include <cstddef>

#define NNODES 100000
#define FIN    512
#define HID    256
#define NCLS   64
#define KSTEPS 10
#define ALPHA  0.1f

// ---------------- Tiled f32 GEMM: C = act(A @ B + bias) ----------------
template<bool RELU>
__global__ __launch_bounds__(256)
void gemm_bias(const float* __restrict__ A, const float* __restrict__ B,
               const float* __restrict__ bias, float* __restrict__ C,
               int M, int K, int N) {
  __shared__ float As[16][68];
  __shared__ float Bs[16][68];
  const int tid = threadIdx.x;
  const int tx = tid & 15;
  const int ty = tid >> 4;
  const int row0 = blockIdx.y * 64;
  const int col0 = blockIdx.x * 64;

  float acc[4][4] = {};

  for (int k0 = 0; k0 < K; k0 += 16) {
#pragma unroll
    for (int i = 0; i < 4; ++i) {
      int idx = tid + i * 256;
      int r = idx >> 4;
      int c = idx & 15;
      int gr = row0 + r;
      As[c][r] = (gr < M) ? A[(size_t)gr * K + (k0 + c)] : 0.f;
    }
#pragma unroll
    for (int i = 0; i < 4; ++i) {
      int idx = tid + i * 256;
      int rk = idx >> 6;
      int cn = idx & 63;
      Bs[rk][cn] = B[(size_t)(k0 + rk) * N + (col0 + cn)];
    }
    __syncthreads();
#pragma unroll
    for (int kk = 0; kk < 16; ++kk) {
      const float4 av = *(const float4*)&As[kk][ty * 4];
      const float4 bv = *(const float4*)&Bs[kk][tx * 4];
      const float a4[4] = {av.x, av.y, av.z, av.w};
      const float b4[4] = {bv.x, bv.y, bv.z, bv.w};
#pragma unroll
      for (int i = 0; i < 4; ++i)
#pragma unroll
        for (int j = 0; j < 4; ++j)
          acc[i][j] = fmaf(a4[i], b4[j], acc[i][j]);
    }
    __syncthreads();
  }

  const int gc = col0 + tx * 4;
  const float4 bv = *(const float4*)&bias[gc];
#pragma unroll
  for (int i = 0; i < 4; ++i) {
    int gr = row0 + ty * 4 + i;
    if (gr < M) {
      float4 v;
      v.x = acc[i][0] + bv.x;
      v.y = acc[i][1] + bv.y;
      v.z = acc[i][2] + bv.z;
      v.w = acc[i][3] + bv.w;
      if (RELU) {
        v.x = fmaxf(v.x, 0.f); v.y = fmaxf(v.y, 0.f);
        v.z = fmaxf(v.z, 0.f); v.w = fmaxf(v.w, 0.f);
      }
      *(float4*)&C[(size_t)gr * N + gc] = v;
    }
  }
}

// ---------------- CSR build ----------------
__global__ void count_deg(const int* __restrict__ dst, unsigned* __restrict__ deg, int E) {
  int e = blockIdx.x * 256 + threadIdx.x;
  if (e < E) atomicAdd(&deg[dst[e]], 1u);
}

// reads deg, writes: norm = rsqrt(deg+1), start (overwrites deg), cursor = start
__global__ void seg_assign(unsigned* __restrict__ degstart, unsigned* __restrict__ cursor,
                           float* __restrict__ norm, unsigned* __restrict__ counter, int n) {
  int i = blockIdx.x * 256 + threadIdx.x;
  if (i >= n) return;
  unsigned d = degstart[i];
  norm[i] = rsqrtf((float)(d + 1u));     // +1 self-loop
  unsigned s = atomicAdd(counter, d);    // order-free segment placement
  degstart[i] = s;
  cursor[i] = s;
}

__global__ void scatter_edges(const int* __restrict__ src, const int* __restrict__ dst,
                              unsigned* __restrict__ cursor, int* __restrict__ col, int E) {
  int e = blockIdx.x * 256 + threadIdx.x;
  if (e >= E) return;
  int d = dst[e];
  unsigned p = atomicAdd(&cursor[d], 1u);
  col[p] = src[e];
}

// ---------------- pull-based propagation, fused finalize ----------------
// one wave per node; lane = channel. h_new = (1-a)*norm*(sum_{src} norm[src]*h[src] + norm*h_self) + a*h0
__global__ __launch_bounds__(256)
void appnp_pull(const float* __restrict__ h, const float* __restrict__ h0,
                const float* __restrict__ norm,
                const unsigned* __restrict__ start, const unsigned* __restrict__ endp,
                const int* __restrict__ col, float* __restrict__ h_new) {
  int wid = (blockIdx.x * 256 + threadIdx.x) >> 6;
  int lane = threadIdx.x & 63;
  if (wid >= NNODES) return;
  unsigned j = start[wid];
  const unsigned j1 = endp[wid];
  float acc = 0.f;
  for (; j + 4 <= j1; j += 4) {
    int a = col[j], b = col[j + 1], c = col[j + 2], d = col[j + 3];
    float na = norm[a], nb = norm[b], nc = norm[c], nd = norm[d];
    float ha = h[(size_t)a * NCLS + lane];
    float hb = h[(size_t)b * NCLS + lane];
    float hc = h[(size_t)c * NCLS + lane];
    float hd = h[(size_t)d * NCLS + lane];
    acc = fmaf(na, ha, acc);
    acc = fmaf(nb, hb, acc);
    acc = fmaf(nc, hc, acc);
    acc = fmaf(nd, hd, acc);
  }
  for (; j < j1; ++j) {
    int a = col[j];
    acc = fmaf(norm[a], h[(size_t)a * NCLS + lane], acc);
  }
  float ni = norm[wid];
  size_t idx = (size_t)wid * NCLS + lane;
  acc = fmaf(ni, h[idx], acc);                       // self-loop
  h_new[idx] = fmaf((1.0f - ALPHA) * ni, acc, ALPHA * h0[idx]);
}

// ---------------- log_softmax (one wave per row, C = 64) ----------------
__global__ __launch_bounds__(256)
void log_softmax_k(const float* __restrict__ h, float* __restrict__ out, int n) {
  int wave = threadIdx.x >> 6;
  int lane = threadIdx.x & 63;
  int row = blockIdx.x * 4 + wave;
  if (row >= n) return;
  float x = h[(size_t)row * NCLS + lane];
  float m = x;
#pragma unroll
  for (int o = 32; o; o >>= 1) m = fmaxf(m, __shfl_xor(m, o, 64));
  float ex = expf(x - m);
  float s = ex;
#pragma unroll
  for (int o = 32; o; o >>= 1) s += __shfl_xor(s, o, 64);
  out[(size_t)row * NCLS + lane] = x - m - logf(s);
}

// ---------------- launch ----------------
extern "C" void kernel_launch(void* const* d_in, const int* in_sizes, int n_in,
                              void* d_out, int out_size, void* d_ws, size_t ws_size,
                              hipStream_t stream) {
  (void)n_in; (void)out_size; (void)ws_size;
  const float* feat = (const float*)d_in[0];
  const float* w1   = (const float*)d_in[1];
  const float* b1   = (const float*)d_in[2];
  const float* w2   = (const float*)d_in[3];
  const float* b2   = (const float*)d_in[4];
  const int*   src  = (const int*)d_in[5];
  const int*   dst  = (const int*)d_in[6];
  const int E = in_sizes[5];
  float* out = (float*)d_out;

  // workspace layout
  char* ws = (char*)d_ws;
  size_t off = 0;
  float* norm = (float*)(ws + off);       off += ((size_t)NNODES * 4 + 255) & ~(size_t)255;
  unsigned* degstart = (unsigned*)(ws + off); off += ((size_t)NNODES * 4 + 255) & ~(size_t)255;
  unsigned* cursor   = (unsigned*)(ws + off); off += ((size_t)NNODES * 4 + 255) & ~(size_t)255;
  unsigned* counter  = (unsigned*)(ws + off); off += 256;
  float* h0 = (float*)(ws + off);         off += (size_t)NNODES * NCLS * 4;
  float* h1 = (float*)(ws + off);         // N*HID floats: MLP intermediate region
  // alias ping-pong buffers + col inside the h1 region (h1 dead after GEMM2,
  // and CSR build runs after GEMM2 so col doesn't get clobbered)
  float* pb0 = h1;
  float* pb1 = (float*)((char*)h1 + (size_t)NNODES * NCLS * 4);
  int*   col = (int*)((char*)h1 + (size_t)2 * NNODES * NCLS * 4);

  // ---- MLP encoder (first: h1 region is scratch for it) ----
  dim3 g1(HID / 64, (NNODES + 63) / 64);
  gemm_bias<true><<<g1, 256, 0, stream>>>(feat, w1, b1, h1, NNODES, FIN, HID);
  dim3 g2(NCLS / 64, (NNODES + 63) / 64);
  gemm_bias<false><<<g2, 256, 0, stream>>>(h1, w2, b2, h0, NNODES, HID, NCLS);

  // ---- CSR build (grouped by dst, segment order arbitrary) ----
  hipMemsetAsync(degstart, 0, (size_t)NNODES * 4, stream);
  hipMemsetAsync(counter, 0, 256, stream);
  count_deg<<<(E + 255) / 256, 256, 0, stream>>>(dst, degstart, E);
  seg_assign<<<(NNODES + 255) / 256, 256, 0, stream>>>(degstart, cursor, norm, counter, NNODES);
  scatter_edges<<<(E + 255) / 256, 256, 0, stream>>>(src, dst, cursor, col, E);
  // after scatter: degstart = segment start, cursor = segment end

  // ---- APPNP propagation (pull) ----
  const float* cur = h0;
  float* bufs[2] = {pb0, pb1};
  const int nblocks = (NNODES * 64 + 255) / 256;
  for (int k = 0; k < KSTEPS; ++k) {
    float* nxt = bufs[k & 1];
    appnp_pull<<<nblocks, 256, 0, stream>>>(cur, h0, norm, degstart, cursor, col, nxt);
    cur = nxt;
  }

  // ---- log_softmax ----
  log_softmax_k<<<(NNODES + 3) / 4, 256, 0, stream>>>(cur, out, NNODES);
}

// Round 3
// 2134.979 us; speedup vs baseline: 13.1025x; 1.0528x over previous
//
#include <hip/hip_runtime.h>
#include <cstdint>
#include <cstddef>

#define NNODES 100000
#define FIN    512
#define HID    256
#define NCLS   64
#define KSTEPS 10
#define ALPHA  0.1f

typedef __bf16 bf16;
typedef __attribute__((ext_vector_type(4))) __bf16 bf16x4;
typedef __attribute__((ext_vector_type(8))) __bf16 bf16x8;
typedef __attribute__((ext_vector_type(4))) float f32x4;

// ---------------- transpose + f32->bf16 convert for weights ----------------
// W [K][N] f32  ->  Wt [N][K] bf16
__global__ void transpose_bf16(const float* __restrict__ W, bf16* __restrict__ Wt,
                               int K, int N) {
  int idx = blockIdx.x * 256 + threadIdx.x;
  if (idx >= K * N) return;
  int k = idx / N, n = idx % N;
  Wt[(size_t)n * K + k] = (bf16)W[idx];
}

// ---------------- MFMA GEMM: C = act(A @ Bt^T + bias) ----------------
// A [M][K] (f32 or bf16), Bt [N][K] bf16 (pre-transposed), C [M][N].
// BM=128 BN=64 BK=32; 4 waves, each 64x32 (4x2 tiles of 16x16x32 mfma).
template<bool A_IS_BF16, bool RELU, bool OUT_BF16>
__global__ __launch_bounds__(256)
void mfma_gemm(const void* __restrict__ Av, const bf16* __restrict__ Bt,
               const float* __restrict__ bias, void* __restrict__ Cv,
               int M, int K, int N) {
  __shared__ bf16 As[128][40];   // [m][k], stride 40 (80B, 16B-aligned, 2-way banks)
  __shared__ bf16 Bs[64][40];    // [n][k]
  const int tid  = threadIdx.x;
  const int lane = tid & 63;
  const int wave = tid >> 6;
  const int wm = wave >> 1;      // 0..1 (m half)
  const int wn = wave & 1;       // 0..1 (n half)
  const int row0 = blockIdx.y * 128;
  const int col0 = blockIdx.x * 64;
  const int l15  = lane & 15;
  const int quad = lane >> 4;

  f32x4 acc[4][2] = {};

  for (int k0 = 0; k0 < K; k0 += 32) {
    // ---- stage A tile 128x32 ----
    if constexpr (!A_IS_BF16) {
      const float* A = (const float*)Av;
#pragma unroll
      for (int i = 0; i < 4; ++i) {
        int idx = tid + i * 256;        // 0..1023
        int r = idx >> 3, c4 = idx & 7; // row 0..127, float4-col 0..7
        int gr = row0 + r;
        float4 v = make_float4(0.f, 0.f, 0.f, 0.f);
        if (gr < M) v = *(const float4*)&A[(size_t)gr * K + k0 + c4 * 4];
        bf16x4 b;
        b[0] = (bf16)v.x; b[1] = (bf16)v.y; b[2] = (bf16)v.z; b[3] = (bf16)v.w;
        *(bf16x4*)&As[r][c4 * 4] = b;
      }
    } else {
      const bf16* A = (const bf16*)Av;
#pragma unroll
      for (int i = 0; i < 2; ++i) {
        int idx = tid + i * 256;         // 0..511
        int r = idx >> 2, k16 = idx & 3; // row 0..127, 16B-chunk 0..3
        int gr = row0 + r;
        bf16x8 v = {};
        if (gr < M) v = *(const bf16x8*)&A[(size_t)gr * K + k0 + k16 * 8];
        *(bf16x8*)&As[r][k16 * 8] = v;
      }
    }
    // ---- stage B tile 64x32 (from Bt [N][K], k-contiguous) ----
    {
      int nrow = tid >> 2, k16 = tid & 3;
      bf16x8 v = *(const bf16x8*)&Bt[(size_t)(col0 + nrow) * K + k0 + k16 * 8];
      *(bf16x8*)&Bs[nrow][k16 * 8] = v;
    }
    __syncthreads();

    bf16x8 af[4], bfr[2];
#pragma unroll
    for (int mt = 0; mt < 4; ++mt)
      af[mt] = *(const bf16x8*)&As[wm * 64 + mt * 16 + l15][quad * 8];
#pragma unroll
    for (int nt = 0; nt < 2; ++nt)
      bfr[nt] = *(const bf16x8*)&Bs[wn * 32 + nt * 16 + l15][quad * 8];
#pragma unroll
    for (int mt = 0; mt < 4; ++mt)
#pragma unroll
      for (int nt = 0; nt < 2; ++nt)
        acc[mt][nt] = __builtin_amdgcn_mfma_f32_16x16x32_bf16(af[mt], bfr[nt],
                                                              acc[mt][nt], 0, 0, 0);
    __syncthreads();
  }

  // ---- epilogue: bias (+relu), store f32 or bf16 ----
#pragma unroll
  for (int nt = 0; nt < 2; ++nt) {
    int gc = col0 + wn * 32 + nt * 16 + l15;
    float bv = bias[gc];
#pragma unroll
    for (int mt = 0; mt < 4; ++mt) {
#pragma unroll
      for (int r = 0; r < 4; ++r) {
        int gr = row0 + wm * 64 + mt * 16 + quad * 4 + r;
        if (gr < M) {
          float v = acc[mt][nt][r] + bv;
          if (RELU) v = fmaxf(v, 0.f);
          if (OUT_BF16) ((bf16*)Cv)[(size_t)gr * N + gc] = (bf16)v;
          else          ((float*)Cv)[(size_t)gr * N + gc] = v;
        }
      }
    }
  }
}

// ---------------- CSR build ----------------
__global__ void count_deg(const int* __restrict__ dst, unsigned* __restrict__ deg, int E) {
  int e = blockIdx.x * 256 + threadIdx.x;
  if (e < E) atomicAdd(&deg[dst[e]], 1u);
}

__global__ void seg_assign(unsigned* __restrict__ degstart, unsigned* __restrict__ cursor,
                           float* __restrict__ norm, unsigned* __restrict__ counter, int n) {
  int i = blockIdx.x * 256 + threadIdx.x;
  if (i >= n) return;
  unsigned d = degstart[i];
  norm[i] = rsqrtf((float)(d + 1u));     // +1 self-loop
  unsigned s = atomicAdd(counter, d);    // order-free segment placement
  degstart[i] = s;
  cursor[i] = s;
}

__global__ void scatter_edges(const int* __restrict__ src, const int* __restrict__ dst,
                              unsigned* __restrict__ cursor, int* __restrict__ col, int E) {
  int e = blockIdx.x * 256 + threadIdx.x;
  if (e >= E) return;
  int d = dst[e];
  unsigned p = atomicAdd(&cursor[d], 1u);
  col[p] = src[e];
}

// ---------------- pull-based propagation, fused finalize ----------------
__global__ __launch_bounds__(256)
void appnp_pull(const float* __restrict__ h, const float* __restrict__ h0,
                const float* __restrict__ norm,
                const unsigned* __restrict__ start, const unsigned* __restrict__ endp,
                const int* __restrict__ col, float* __restrict__ h_new) {
  int wid = (blockIdx.x * 256 + threadIdx.x) >> 6;
  int lane = threadIdx.x & 63;
  if (wid >= NNODES) return;
  unsigned j = start[wid];
  const unsigned j1 = endp[wid];
  float acc = 0.f;
  for (; j + 4 <= j1; j += 4) {
    int a = col[j], b = col[j + 1], c = col[j + 2], d = col[j + 3];
    float na = norm[a], nb = norm[b], nc = norm[c], nd = norm[d];
    float ha = h[(size_t)a * NCLS + lane];
    float hb = h[(size_t)b * NCLS + lane];
    float hc = h[(size_t)c * NCLS + lane];
    float hd = h[(size_t)d * NCLS + lane];
    acc = fmaf(na, ha, acc);
    acc = fmaf(nb, hb, acc);
    acc = fmaf(nc, hc, acc);
    acc = fmaf(nd, hd, acc);
  }
  for (; j < j1; ++j) {
    int a = col[j];
    acc = fmaf(norm[a], h[(size_t)a * NCLS + lane], acc);
  }
  float ni = norm[wid];
  size_t idx = (size_t)wid * NCLS + lane;
  acc = fmaf(ni, h[idx], acc);                       // self-loop
  h_new[idx] = fmaf((1.0f - ALPHA) * ni, acc, ALPHA * h0[idx]);
}

// ---------------- log_softmax ----------------
__global__ __launch_bounds__(256)
void log_softmax_k(const float* __restrict__ h, float* __restrict__ out, int n) {
  int wave = threadIdx.x >> 6;
  int lane = threadIdx.x & 63;
  int row = blockIdx.x * 4 + wave;
  if (row >= n) return;
  float x = h[(size_t)row * NCLS + lane];
  float m = x;
#pragma unroll
  for (int o = 32; o; o >>= 1) m = fmaxf(m, __shfl_xor(m, o, 64));
  float ex = expf(x - m);
  float s = ex;
#pragma unroll
  for (int o = 32; o; o >>= 1) s += __shfl_xor(s, o, 64);
  out[(size_t)row * NCLS + lane] = x - m - logf(s);
}

// ---------------- launch ----------------
extern "C" void kernel_launch(void* const* d_in, const int* in_sizes, int n_in,
                              void* d_out, int out_size, void* d_ws, size_t ws_size,
                              hipStream_t stream) {
  (void)n_in; (void)out_size; (void)ws_size;
  const float* feat = (const float*)d_in[0];
  const float* w1   = (const float*)d_in[1];
  const float* b1   = (const float*)d_in[2];
  const float* w2   = (const float*)d_in[3];
  const float* b2   = (const float*)d_in[4];
  const int*   src  = (const int*)d_in[5];
  const int*   dst  = (const int*)d_in[6];
  const int E = in_sizes[5];
  float* out = (float*)d_out;

  // workspace layout
  char* ws = (char*)d_ws;
  size_t off = 0;
  float* norm = (float*)(ws + off);           off += ((size_t)NNODES * 4 + 255) & ~(size_t)255;
  unsigned* degstart = (unsigned*)(ws + off); off += ((size_t)NNODES * 4 + 255) & ~(size_t)255;
  unsigned* cursor   = (unsigned*)(ws + off); off += ((size_t)NNODES * 4 + 255) & ~(size_t)255;
  unsigned* counter  = (unsigned*)(ws + off); off += 256;
  float* h0 = (float*)(ws + off);             off += (size_t)NNODES * NCLS * 4;
  float* pb0 = (float*)(ws + off);            off += (size_t)NNODES * NCLS * 4;
  float* pb1 = (float*)(ws + off);            off += (size_t)NNODES * NCLS * 4;
  int*   col = (int*)(ws + off);              off += ((size_t)E * 4 + 255) & ~(size_t)255;
  bf16* w1t  = (bf16*)(ws + off);             off += ((size_t)HID * FIN * 2 + 255) & ~(size_t)255;
  bf16* w2t  = (bf16*)(ws + off);             off += ((size_t)NCLS * HID * 2 + 255) & ~(size_t)255;
  // h1b (bf16 MLP intermediate, 51.2MB) aliases the pb0+pb1 region (dead then)
  bf16* h1b = (bf16*)pb0;

  // ---- weight transpose/convert (tiny) ----
  transpose_bf16<<<(FIN * HID + 255) / 256, 256, 0, stream>>>(w1, w1t, FIN, HID);
  transpose_bf16<<<(HID * NCLS + 255) / 256, 256, 0, stream>>>(w2, w2t, HID, NCLS);

  // ---- MLP encoder (bf16 MFMA) ----
  dim3 g1(HID / 64, (NNODES + 127) / 128);
  mfma_gemm<false, true, true><<<g1, 256, 0, stream>>>(feat, w1t, b1, h1b,
                                                       NNODES, FIN, HID);
  dim3 g2(NCLS / 64, (NNODES + 127) / 128);
  mfma_gemm<true, false, false><<<g2, 256, 0, stream>>>(h1b, w2t, b2, h0,
                                                        NNODES, HID, NCLS);

  // ---- CSR build (grouped by dst) ----
  hipMemsetAsync(degstart, 0, (size_t)NNODES * 4, stream);
  hipMemsetAsync(counter, 0, 256, stream);
  count_deg<<<(E + 255) / 256, 256, 0, stream>>>(dst, degstart, E);
  seg_assign<<<(NNODES + 255) / 256, 256, 0, stream>>>(degstart, cursor, norm, counter, NNODES);
  scatter_edges<<<(E + 255) / 256, 256, 0, stream>>>(src, dst, cursor, col, E);

  // ---- APPNP propagation (pull) ----
  const float* cur = h0;
  float* bufs[2] = {pb0, pb1};
  const int nblocks = (NNODES * 64 + 255) / 256;
  for (int k = 0; k < KSTEPS; ++k) {
    float* nxt = bufs[k & 1];
    appnp_pull<<<nblocks, 256, 0, stream>>>(cur, h0, norm, degstart, cursor, col, nxt);
    cur = nxt;
  }

  // ---- log_softmax ----
  log_softmax_k<<<(NNODES + 3) / 4, 256, 0, stream>>>(cur, out, NNODES);
}

// Round 4
// 1868.785 us; speedup vs baseline: 14.9688x; 1.1424x over previous
//
#include <hip/hip_runtime.h>
#include <cstdint>
#include <cstddef>

#define NNODES 100000
#define FIN    512
#define HID    256
#define NCLS   64
#define KSTEPS 10
#define ALPHA  0.1f

typedef __bf16 bf16;
typedef __attribute__((ext_vector_type(4))) __bf16 bf16x4;
typedef __attribute__((ext_vector_type(8))) __bf16 bf16x8;
typedef __attribute__((ext_vector_type(4))) float f32x4;

// ---------------- transpose + f32->bf16 convert for weights ----------------
// W [K][N] f32  ->  Wt [N][K] bf16
__global__ void transpose_bf16(const float* __restrict__ W, bf16* __restrict__ Wt,
                               int K, int N) {
  int idx = blockIdx.x * 256 + threadIdx.x;
  if (idx >= K * N) return;
  int k = idx / N, n = idx % N;
  Wt[(size_t)n * K + k] = (bf16)W[idx];
}

// ---------------- f32 -> bf16 bulk convert (4 elems/thread) ----------------
__global__ void f32_to_bf16(const float* __restrict__ in, bf16* __restrict__ outp, int n4) {
  int i = blockIdx.x * 256 + threadIdx.x;
  if (i >= n4) return;
  float4 v = *(const float4*)&in[(size_t)i * 4];
  bf16x4 b;
  b[0] = (bf16)v.x; b[1] = (bf16)v.y; b[2] = (bf16)v.z; b[3] = (bf16)v.w;
  *(bf16x4*)&outp[(size_t)i * 4] = b;
}

// ---------------- MFMA GEMM: C = act(A @ Bt^T + bias) ----------------
// A [M][K] (f32 or bf16), Bt [N][K] bf16 (pre-transposed), C [M][N].
// BM=128 BN=64 BK=32; 4 waves, each 64x32 (4x2 tiles of 16x16x32 mfma).
template<bool A_IS_BF16, bool RELU, bool OUT_BF16>
__global__ __launch_bounds__(256)
void mfma_gemm(const void* __restrict__ Av, const bf16* __restrict__ Bt,
               const float* __restrict__ bias, void* __restrict__ Cv,
               int M, int K, int N) {
  __shared__ bf16 As[128][40];   // [m][k], stride 40 (80B, 16B-aligned, 2-way banks)
  __shared__ bf16 Bs[64][40];    // [n][k]
  const int tid  = threadIdx.x;
  const int lane = tid & 63;
  const int wave = tid >> 6;
  const int wm = wave >> 1;      // 0..1 (m half)
  const int wn = wave & 1;       // 0..1 (n half)
  const int row0 = blockIdx.y * 128;
  const int col0 = blockIdx.x * 64;
  const int l15  = lane & 15;
  const int quad = lane >> 4;

  f32x4 acc[4][2] = {};

  for (int k0 = 0; k0 < K; k0 += 32) {
    if constexpr (!A_IS_BF16) {
      const float* A = (const float*)Av;
#pragma unroll
      for (int i = 0; i < 4; ++i) {
        int idx = tid + i * 256;        // 0..1023
        int r = idx >> 3, c4 = idx & 7; // row 0..127, float4-col 0..7
        int gr = row0 + r;
        float4 v = make_float4(0.f, 0.f, 0.f, 0.f);
        if (gr < M) v = *(const float4*)&A[(size_t)gr * K + k0 + c4 * 4];
        bf16x4 b;
        b[0] = (bf16)v.x; b[1] = (bf16)v.y; b[2] = (bf16)v.z; b[3] = (bf16)v.w;
        *(bf16x4*)&As[r][c4 * 4] = b;
      }
    } else {
      const bf16* A = (const bf16*)Av;
#pragma unroll
      for (int i = 0; i < 2; ++i) {
        int idx = tid + i * 256;         // 0..511
        int r = idx >> 2, k16 = idx & 3; // row 0..127, 16B-chunk 0..3
        int gr = row0 + r;
        bf16x8 v = {};
        if (gr < M) v = *(const bf16x8*)&A[(size_t)gr * K + k0 + k16 * 8];
        *(bf16x8*)&As[r][k16 * 8] = v;
      }
    }
    {
      int nrow = tid >> 2, k16 = tid & 3;
      bf16x8 v = *(const bf16x8*)&Bt[(size_t)(col0 + nrow) * K + k0 + k16 * 8];
      *(bf16x8*)&Bs[nrow][k16 * 8] = v;
    }
    __syncthreads();

    bf16x8 af[4], bfr[2];
#pragma unroll
    for (int mt = 0; mt < 4; ++mt)
      af[mt] = *(const bf16x8*)&As[wm * 64 + mt * 16 + l15][quad * 8];
#pragma unroll
    for (int nt = 0; nt < 2; ++nt)
      bfr[nt] = *(const bf16x8*)&Bs[wn * 32 + nt * 16 + l15][quad * 8];
#pragma unroll
    for (int mt = 0; mt < 4; ++mt)
#pragma unroll
      for (int nt = 0; nt < 2; ++nt)
        acc[mt][nt] = __builtin_amdgcn_mfma_f32_16x16x32_bf16(af[mt], bfr[nt],
                                                              acc[mt][nt], 0, 0, 0);
    __syncthreads();
  }

#pragma unroll
  for (int nt = 0; nt < 2; ++nt) {
    int gc = col0 + wn * 32 + nt * 16 + l15;
    float bv = bias[gc];
#pragma unroll
    for (int mt = 0; mt < 4; ++mt) {
#pragma unroll
      for (int r = 0; r < 4; ++r) {
        int gr = row0 + wm * 64 + mt * 16 + quad * 4 + r;
        if (gr < M) {
          float v = acc[mt][nt][r] + bv;
          if (RELU) v = fmaxf(v, 0.f);
          if (OUT_BF16) ((bf16*)Cv)[(size_t)gr * N + gc] = (bf16)v;
          else          ((float*)Cv)[(size_t)gr * N + gc] = v;
        }
      }
    }
  }
}

// ---------------- CSR build ----------------
__global__ void count_deg(const int* __restrict__ dst, unsigned* __restrict__ deg, int E) {
  int e = blockIdx.x * 256 + threadIdx.x;
  if (e < E) atomicAdd(&deg[dst[e]], 1u);
}

__global__ void seg_assign(unsigned* __restrict__ degstart, unsigned* __restrict__ cursor,
                           float* __restrict__ norm, unsigned* __restrict__ counter, int n) {
  int i = blockIdx.x * 256 + threadIdx.x;
  if (i >= n) return;
  unsigned d = degstart[i];
  norm[i] = rsqrtf((float)(d + 1u));     // +1 self-loop
  unsigned s = atomicAdd(counter, d);    // order-free segment placement
  degstart[i] = s;
  cursor[i] = s;
}

__global__ void scatter_edges(const int* __restrict__ src, const int* __restrict__ dst,
                              unsigned* __restrict__ cursor, int* __restrict__ col, int E) {
  int e = blockIdx.x * 256 + threadIdx.x;
  if (e >= E) return;
  int d = dst[e];
  unsigned p = atomicAdd(&cursor[d], 1u);
  col[p] = src[e];
}

// ---------------- pull-based propagation (bf16 state), fused finalize ----------------
// one wave per node; lane = channel.
// h_new = (1-a)*norm*(sum_{src} norm[src]*h[src] + norm*h_self) + a*h0f
__global__ __launch_bounds__(256)
void appnp_pull_bf16(const bf16* __restrict__ h, const float* __restrict__ h0f,
                     const float* __restrict__ norm,
                     const unsigned* __restrict__ start, const unsigned* __restrict__ endp,
                     const int* __restrict__ col, bf16* __restrict__ h_new) {
  int wid = (blockIdx.x * 256 + threadIdx.x) >> 6;
  int lane = threadIdx.x & 63;
  if (wid >= NNODES) return;
  unsigned j = start[wid];
  const unsigned j1 = endp[wid];
  float acc = 0.f;
  for (; j + 4 <= j1; j += 4) {
    int a = col[j], b = col[j + 1], c = col[j + 2], d = col[j + 3];
    float na = norm[a], nb = norm[b], nc = norm[c], nd = norm[d];
    float ha = (float)h[(size_t)a * NCLS + lane];
    float hb = (float)h[(size_t)b * NCLS + lane];
    float hc = (float)h[(size_t)c * NCLS + lane];
    float hd = (float)h[(size_t)d * NCLS + lane];
    acc = fmaf(na, ha, acc);
    acc = fmaf(nb, hb, acc);
    acc = fmaf(nc, hc, acc);
    acc = fmaf(nd, hd, acc);
  }
  for (; j < j1; ++j) {
    int a = col[j];
    acc = fmaf(norm[a], (float)h[(size_t)a * NCLS + lane], acc);
  }
  float ni = norm[wid];
  size_t idx = (size_t)wid * NCLS + lane;
  acc = fmaf(ni, (float)h[idx], acc);                // self-loop
  float v = fmaf((1.0f - ALPHA) * ni, acc, ALPHA * h0f[idx]);
  h_new[idx] = (bf16)v;
}

// ---------------- log_softmax (bf16 in, f32 out) ----------------
__global__ __launch_bounds__(256)
void log_softmax_k(const bf16* __restrict__ h, float* __restrict__ out, int n) {
  int wave = threadIdx.x >> 6;
  int lane = threadIdx.x & 63;
  int row = blockIdx.x * 4 + wave;
  if (row >= n) return;
  float x = (float)h[(size_t)row * NCLS + lane];
  float m = x;
#pragma unroll
  for (int o = 32; o; o >>= 1) m = fmaxf(m, __shfl_xor(m, o, 64));
  float ex = expf(x - m);
  float s = ex;
#pragma unroll
  for (int o = 32; o; o >>= 1) s += __shfl_xor(s, o, 64);
  out[(size_t)row * NCLS + lane] = x - m - logf(s);
}

// ---------------- launch ----------------
extern "C" void kernel_launch(void* const* d_in, const int* in_sizes, int n_in,
                              void* d_out, int out_size, void* d_ws, size_t ws_size,
                              hipStream_t stream) {
  (void)n_in; (void)out_size; (void)ws_size;
  const float* feat = (const float*)d_in[0];
  const float* w1   = (const float*)d_in[1];
  const float* b1   = (const float*)d_in[2];
  const float* w2   = (const float*)d_in[3];
  const float* b2   = (const float*)d_in[4];
  const int*   src  = (const int*)d_in[5];
  const int*   dst  = (const int*)d_in[6];
  const int E = in_sizes[5];
  float* out = (float*)d_out;

  // workspace layout (~79 MB total)
  char* ws = (char*)d_ws;
  size_t off = 0;
  float* norm = (float*)(ws + off);           off += ((size_t)NNODES * 4 + 255) & ~(size_t)255;
  unsigned* degstart = (unsigned*)(ws + off); off += ((size_t)NNODES * 4 + 255) & ~(size_t)255;
  unsigned* cursor   = (unsigned*)(ws + off); off += ((size_t)NNODES * 4 + 255) & ~(size_t)255;
  unsigned* counter  = (unsigned*)(ws + off); off += 256;
  float* h0f = (float*)(ws + off);            off += (size_t)NNODES * NCLS * 4;   // 25.6 MB
  // X region (51.2 MB): during MLP it is h1b [N][HID] bf16; afterwards it is
  // { pb0, pb1, col, h0b } (each 12.8 MB). GEMM2 finishes reading h1b before
  // anything below is written (f32_to_bf16 / CSR build run after GEMM2).
  char* X = ws + off;                         off += (size_t)NNODES * HID * 2;
  bf16* h1b = (bf16*)X;
  bf16* pb0 = (bf16*)X;
  bf16* pb1 = (bf16*)(X + (size_t)NNODES * NCLS * 2);
  int*  col = (int*) (X + (size_t)2 * NNODES * NCLS * 2);
  bf16* h0b = (bf16*)(X + (size_t)2 * NNODES * NCLS * 2 + (size_t)NNODES * NCLS * 4);
  bf16* w1t  = (bf16*)(ws + off);             off += ((size_t)HID * FIN * 2 + 255) & ~(size_t)255;
  bf16* w2t  = (bf16*)(ws + off);             off += ((size_t)NCLS * HID * 2 + 255) & ~(size_t)255;

  // ---- weight transpose/convert (tiny) ----
  transpose_bf16<<<(FIN * HID + 255) / 256, 256, 0, stream>>>(w1, w1t, FIN, HID);
  transpose_bf16<<<(HID * NCLS + 255) / 256, 256, 0, stream>>>(w2, w2t, HID, NCLS);

  // ---- MLP encoder (bf16 MFMA) ----
  dim3 g1(HID / 64, (NNODES + 127) / 128);
  mfma_gemm<false, true, true><<<g1, 256, 0, stream>>>(feat, w1t, b1, h1b,
                                                       NNODES, FIN, HID);
  dim3 g2(NCLS / 64, (NNODES + 127) / 128);
  mfma_gemm<true, false, false><<<g2, 256, 0, stream>>>(h1b, w2t, b2, h0f,
                                                        NNODES, HID, NCLS);

  // ---- h0 bf16 copy (h1b dead now) ----
  f32_to_bf16<<<(NNODES * NCLS / 4 + 255) / 256, 256, 0, stream>>>(h0f, h0b,
                                                                   NNODES * NCLS / 4);

  // ---- CSR build (grouped by dst) ----
  hipMemsetAsync(degstart, 0, (size_t)NNODES * 4, stream);
  hipMemsetAsync(counter, 0, 256, stream);
  count_deg<<<(E + 255) / 256, 256, 0, stream>>>(dst, degstart, E);
  seg_assign<<<(NNODES + 255) / 256, 256, 0, stream>>>(degstart, cursor, norm, counter, NNODES);
  scatter_edges<<<(E + 255) / 256, 256, 0, stream>>>(src, dst, cursor, col, E);

  // ---- APPNP propagation (pull, bf16 state) ----
  const bf16* cur = h0b;
  bf16* bufs[2] = {pb0, pb1};
  const int nblocks = (NNODES * 64 + 255) / 256;
  for (int k = 0; k < KSTEPS; ++k) {
    bf16* nxt = bufs[k & 1];
    appnp_pull_bf16<<<nblocks, 256, 0, stream>>>(cur, h0f, norm, degstart, cursor, col, nxt);
    cur = nxt;
  }

  // ---- log_softmax ----
  log_softmax_k<<<(NNODES + 3) / 4, 256, 0, stream>>>(cur, out, NNODES);
}

// Round 5
// 1767.869 us; speedup vs baseline: 15.8233x; 1.0571x over previous
//
#include <hip/hip_runtime.h>
#include <cstdint>
#include <cstddef>

#define NNODES 100000
#define FIN    512
#define HID    256
#define NCLS   64
#define KSTEPS 10
#define ALPHA  0.1f

#define NBUCK  1563     // ceil(NNODES/64)
#define BCAP   3072     // mean 2048, std ~45 -> 22 sigma headroom

typedef __bf16 bf16;
typedef __attribute__((ext_vector_type(4))) __bf16 bf16x4;
typedef __attribute__((ext_vector_type(8))) __bf16 bf16x8;
typedef __attribute__((ext_vector_type(4))) float f32x4;

// ---------------- transpose + f32->bf16 convert for weights ----------------
__global__ void transpose_bf16(const float* __restrict__ W, bf16* __restrict__ Wt,
                               int K, int N) {
  int idx = blockIdx.x * 256 + threadIdx.x;
  if (idx >= K * N) return;
  int k = idx / N, n = idx % N;
  Wt[(size_t)n * K + k] = (bf16)W[idx];
}

// ---------------- MFMA GEMM: C = act(A @ Bt^T + bias) ----------------
// A [M][K] (f32 or bf16), Bt [N][K] bf16, outputs optionally f32 and/or bf16.
template<bool A_IS_BF16, bool RELU, bool OUT_F32, bool OUT_BF16>
__global__ __launch_bounds__(256)
void mfma_gemm(const void* __restrict__ Av, const bf16* __restrict__ Bt,
               const float* __restrict__ bias, float* __restrict__ Cf,
               bf16* __restrict__ Cb, int M, int K, int N) {
  __shared__ bf16 As[128][40];
  __shared__ bf16 Bs[64][40];
  const int tid  = threadIdx.x;
  const int lane = tid & 63;
  const int wave = tid >> 6;
  const int wm = wave >> 1;
  const int wn = wave & 1;
  const int row0 = blockIdx.y * 128;
  const int col0 = blockIdx.x * 64;
  const int l15  = lane & 15;
  const int quad = lane >> 4;

  f32x4 acc[4][2] = {};

  for (int k0 = 0; k0 < K; k0 += 32) {
    if constexpr (!A_IS_BF16) {
      const float* A = (const float*)Av;
#pragma unroll
      for (int i = 0; i < 4; ++i) {
        int idx = tid + i * 256;
        int r = idx >> 3, c4 = idx & 7;
        int gr = row0 + r;
        float4 v = make_float4(0.f, 0.f, 0.f, 0.f);
        if (gr < M) v = *(const float4*)&A[(size_t)gr * K + k0 + c4 * 4];
        bf16x4 b;
        b[0] = (bf16)v.x; b[1] = (bf16)v.y; b[2] = (bf16)v.z; b[3] = (bf16)v.w;
        *(bf16x4*)&As[r][c4 * 4] = b;
      }
    } else {
      const bf16* A = (const bf16*)Av;
#pragma unroll
      for (int i = 0; i < 2; ++i) {
        int idx = tid + i * 256;
        int r = idx >> 2, k16 = idx & 3;
        int gr = row0 + r;
        bf16x8 v = {};
        if (gr < M) v = *(const bf16x8*)&A[(size_t)gr * K + k0 + k16 * 8];
        *(bf16x8*)&As[r][k16 * 8] = v;
      }
    }
    {
      int nrow = tid >> 2, k16 = tid & 3;
      bf16x8 v = *(const bf16x8*)&Bt[(size_t)(col0 + nrow) * K + k0 + k16 * 8];
      *(bf16x8*)&Bs[nrow][k16 * 8] = v;
    }
    __syncthreads();

    bf16x8 af[4], bfr[2];
#pragma unroll
    for (int mt = 0; mt < 4; ++mt)
      af[mt] = *(const bf16x8*)&As[wm * 64 + mt * 16 + l15][quad * 8];
#pragma unroll
    for (int nt = 0; nt < 2; ++nt)
      bfr[nt] = *(const bf16x8*)&Bs[wn * 32 + nt * 16 + l15][quad * 8];
#pragma unroll
    for (int mt = 0; mt < 4; ++mt)
#pragma unroll
      for (int nt = 0; nt < 2; ++nt)
        acc[mt][nt] = __builtin_amdgcn_mfma_f32_16x16x32_bf16(af[mt], bfr[nt],
                                                              acc[mt][nt], 0, 0, 0);
    __syncthreads();
  }

#pragma unroll
  for (int nt = 0; nt < 2; ++nt) {
    int gc = col0 + wn * 32 + nt * 16 + l15;
    float bv = bias[gc];
#pragma unroll
    for (int mt = 0; mt < 4; ++mt) {
#pragma unroll
      for (int r = 0; r < 4; ++r) {
        int gr = row0 + wm * 64 + mt * 16 + quad * 4 + r;
        if (gr < M) {
          float v = acc[mt][nt][r] + bv;
          if (RELU) v = fmaxf(v, 0.f);
          if (OUT_F32)  Cf[(size_t)gr * N + gc] = v;
          if (OUT_BF16) Cb[(size_t)gr * N + gc] = (bf16)v;
        }
      }
    }
  }
}

// ---------------- CSR build: bucketed two-pass ----------------
// Pass 1: append (src<<6 | dst&63) into bucket dst>>6. Cursors padded to 64B.
__global__ __launch_bounds__(256)
void bucket_pass1(const int* __restrict__ src, const int* __restrict__ dst,
                  unsigned* __restrict__ bcnt, unsigned* __restrict__ bdata, int E) {
  int e = blockIdx.x * 256 + threadIdx.x;
  if (e >= E) return;
  int s = src[e], d = dst[e];
  int b = d >> 6;
  unsigned p = atomicAdd(&bcnt[b * 16], 1u);
  bdata[(size_t)b * BCAP + p] = ((unsigned)s << 6) | (unsigned)(d & 63);
}

// Pass 2: one block per bucket. LDS histogram over the 64 local nodes,
// single-wave scan, ONE global atomic per bucket for segment placement,
// scatter col into a contiguous (L2-resident) region. Also emits
// norm/start/end per node (degree falls out of the histogram).
__global__ __launch_bounds__(256)
void bucket_pass2(const unsigned* __restrict__ bcnt, const unsigned* __restrict__ bdata,
                  unsigned* __restrict__ counter, float* __restrict__ norm,
                  unsigned* __restrict__ startp, unsigned* __restrict__ endp,
                  int* __restrict__ col) {
  __shared__ unsigned lcnt[64];
  __shared__ unsigned lcur[64];
  const int b = blockIdx.x;
  const int tid = threadIdx.x;
  const unsigned cnt = bcnt[b * 16];
  const unsigned* data = &bdata[(size_t)b * BCAP];

  if (tid < 64) lcnt[tid] = 0;
  __syncthreads();
  for (unsigned i = tid; i < cnt; i += 256)
    atomicAdd(&lcnt[data[i] & 63], 1u);
  __syncthreads();

  if (tid < 64) {
    unsigned v = lcnt[tid];
    unsigned inc = v;
#pragma unroll
    for (int o = 1; o < 64; o <<= 1) {
      unsigned t = __shfl_up(inc, o, 64);
      if (tid >= o) inc += t;
    }
    unsigned base = 0;
    if (tid == 63) base = atomicAdd(counter, inc);   // segment placement, order-free
    base = __shfl(base, 63, 64);
    unsigned st = base + inc - v;                    // global col offset
    lcur[tid] = st;
    int g = b * 64 + tid;
    if (g < NNODES) {
      startp[g] = st;
      endp[g]   = st + v;
      norm[g]   = rsqrtf((float)(v + 1u));           // +1 self-loop
    }
  }
  __syncthreads();
  for (unsigned i = tid; i < cnt; i += 256) {
    unsigned v = data[i];
    unsigned p = atomicAdd(&lcur[v & 63], 1u);       // LDS atomic
    col[p] = (int)(v >> 6);
  }
}

// ---------------- pull-based propagation (bf16 state), fused finalize ----------------
__global__ __launch_bounds__(256)
void appnp_pull_bf16(const bf16* __restrict__ h, const float* __restrict__ h0f,
                     const float* __restrict__ norm,
                     const unsigned* __restrict__ start, const unsigned* __restrict__ endp,
                     const int* __restrict__ col, bf16* __restrict__ h_new) {
  int wid = (blockIdx.x * 256 + threadIdx.x) >> 6;
  int lane = threadIdx.x & 63;
  if (wid >= NNODES) return;
  unsigned j = start[wid];
  const unsigned j1 = endp[wid];
  float acc = 0.f;
  for (; j + 4 <= j1; j += 4) {
    int a = col[j], b = col[j + 1], c = col[j + 2], d = col[j + 3];
    float na = norm[a], nb = norm[b], nc = norm[c], nd = norm[d];
    float ha = (float)h[(size_t)a * NCLS + lane];
    float hb = (float)h[(size_t)b * NCLS + lane];
    float hc = (float)h[(size_t)c * NCLS + lane];
    float hd = (float)h[(size_t)d * NCLS + lane];
    acc = fmaf(na, ha, acc);
    acc = fmaf(nb, hb, acc);
    acc = fmaf(nc, hc, acc);
    acc = fmaf(nd, hd, acc);
  }
  for (; j < j1; ++j) {
    int a = col[j];
    acc = fmaf(norm[a], (float)h[(size_t)a * NCLS + lane], acc);
  }
  float ni = norm[wid];
  size_t idx = (size_t)wid * NCLS + lane;
  acc = fmaf(ni, (float)h[idx], acc);                // self-loop
  float v = fmaf((1.0f - ALPHA) * ni, acc, ALPHA * h0f[idx]);
  h_new[idx] = (bf16)v;
}

// ---------------- log_softmax (bf16 in, f32 out) ----------------
__global__ __launch_bounds__(256)
void log_softmax_k(const bf16* __restrict__ h, float* __restrict__ out, int n) {
  int wave = threadIdx.x >> 6;
  int lane = threadIdx.x & 63;
  int row = blockIdx.x * 4 + wave;
  if (row >= n) return;
  float x = (float)h[(size_t)row * NCLS + lane];
  float m = x;
#pragma unroll
  for (int o = 32; o; o >>= 1) m = fmaxf(m, __shfl_xor(m, o, 64));
  float ex = expf(x - m);
  float s = ex;
#pragma unroll
  for (int o = 32; o; o >>= 1) s += __shfl_xor(s, o, 64);
  out[(size_t)row * NCLS + lane] = x - m - logf(s);
}

// ---------------- launch ----------------
extern "C" void kernel_launch(void* const* d_in, const int* in_sizes, int n_in,
                              void* d_out, int out_size, void* d_ws, size_t ws_size,
                              hipStream_t stream) {
  (void)n_in; (void)out_size; (void)ws_size;
  const float* feat = (const float*)d_in[0];
  const float* w1   = (const float*)d_in[1];
  const float* b1   = (const float*)d_in[2];
  const float* w2   = (const float*)d_in[3];
  const float* b2   = (const float*)d_in[4];
  const int*   src  = (const int*)d_in[5];
  const int*   dst  = (const int*)d_in[6];
  const int E = in_sizes[5];
  float* out = (float*)d_out;

  // workspace layout (~110 MB)
  char* ws = (char*)d_ws;
  size_t off = 0;
  float* norm = (float*)(ws + off);           off += ((size_t)NNODES * 4 + 255) & ~(size_t)255;
  unsigned* startp = (unsigned*)(ws + off);   off += ((size_t)NNODES * 4 + 255) & ~(size_t)255;
  unsigned* endp   = (unsigned*)(ws + off);   off += ((size_t)NNODES * 4 + 255) & ~(size_t)255;
  unsigned* counter = (unsigned*)(ws + off);  off += 256;
  float* h0f = (float*)(ws + off);            off += (size_t)NNODES * NCLS * 4;   // 25.6 MB
  bf16*  h0b = (bf16*)(ws + off);             off += (size_t)NNODES * NCLS * 2;   // 12.8 MB
  // X region (51.2 MB): h1b [N][HID] bf16 during MLP; afterwards {pb0, pb1, col}
  // (written only after GEMM2 has consumed h1b).
  char* X = ws + off;                         off += (size_t)NNODES * HID * 2;
  bf16* h1b = (bf16*)X;
  bf16* pb0 = (bf16*)X;
  bf16* pb1 = (bf16*)(X + (size_t)NNODES * NCLS * 2);
  int*  col = (int*) (X + (size_t)2 * NNODES * NCLS * 2);
  unsigned* bcnt  = (unsigned*)(ws + off);    off += ((size_t)NBUCK * 16 * 4 + 255) & ~(size_t)255;
  unsigned* bdata = (unsigned*)(ws + off);    off += (size_t)NBUCK * BCAP * 4;     // 19.2 MB
  bf16* w1t = (bf16*)(ws + off);              off += ((size_t)HID * FIN * 2 + 255) & ~(size_t)255;
  bf16* w2t = (bf16*)(ws + off);              off += ((size_t)NCLS * HID * 2 + 255) & ~(size_t)255;

  // ---- CSR pass 1 (independent of MLP; bdata/bcnt don't alias X) ----
  hipMemsetAsync(bcnt, 0, (size_t)NBUCK * 16 * 4, stream);
  hipMemsetAsync(counter, 0, 256, stream);
  bucket_pass1<<<(E + 255) / 256, 256, 0, stream>>>(src, dst, bcnt, bdata, E);

  // ---- weight transpose/convert (tiny) ----
  transpose_bf16<<<(FIN * HID + 255) / 256, 256, 0, stream>>>(w1, w1t, FIN, HID);
  transpose_bf16<<<(HID * NCLS + 255) / 256, 256, 0, stream>>>(w2, w2t, HID, NCLS);

  // ---- MLP encoder (bf16 MFMA); GEMM2 emits f32 + bf16 h0 in one pass ----
  dim3 g1(HID / 64, (NNODES + 127) / 128);
  mfma_gemm<false, true, false, true><<<g1, 256, 0, stream>>>(feat, w1t, b1,
                                                              nullptr, h1b,
                                                              NNODES, FIN, HID);
  dim3 g2(NCLS / 64, (NNODES + 127) / 128);
  mfma_gemm<true, false, true, true><<<g2, 256, 0, stream>>>(h1b, w2t, b2,
                                                             h0f, h0b,
                                                             NNODES, HID, NCLS);

  // ---- CSR pass 2 (col aliases X: must run after GEMM2) ----
  bucket_pass2<<<NBUCK, 256, 0, stream>>>(bcnt, bdata, counter, norm,
                                          startp, endp, col);

  // ---- APPNP propagation (pull, bf16 state) ----
  const bf16* cur = h0b;
  bf16* bufs[2] = {pb0, pb1};
  const int nblocks = (NNODES * 64 + 255) / 256;
  for (int k = 0; k < KSTEPS; ++k) {
    bf16* nxt = bufs[k & 1];
    appnp_pull_bf16<<<nblocks, 256, 0, stream>>>(cur, h0f, norm, startp, endp, col, nxt);
    cur = nxt;
  }

  // ---- log_softmax ----
  log_softmax_k<<<(NNODES + 3) / 4, 256, 0, stream>>>(cur, out, NNODES);
}

// Round 6
// 1589.913 us; speedup vs baseline: 17.5943x; 1.1119x over previous
//
#include <hip/hip_runtime.h>
#include <cstdint>
#include <cstddef>

#define NNODES 100000
#define FIN    512
#define HID    256
#define NCLS   64
#define KSTEPS 10
#define ALPHA  0.1f

#define NBUCK  1563     // ceil(NNODES/64)
#define BCAP   3072     // mean 2048, std ~45 -> 22 sigma headroom

typedef __bf16 bf16;
typedef __attribute__((ext_vector_type(4))) __bf16 bf16x4;
typedef __attribute__((ext_vector_type(8))) __bf16 bf16x8;
typedef __attribute__((ext_vector_type(4))) float f32x4;

// ---------------- transpose + f32->bf16 convert for weights ----------------
__global__ void transpose_bf16(const float* __restrict__ W, bf16* __restrict__ Wt,
                               int K, int N) {
  int idx = blockIdx.x * 256 + threadIdx.x;
  if (idx >= K * N) return;
  int k = idx / N, n = idx % N;
  Wt[(size_t)n * K + k] = (bf16)W[idx];
}

// ---------------- GEMM1: h1 = relu(feat @ w1t^T + b1), BM=64 BN=256 ----------------
// Full N per block -> A fetched exactly once from HBM.
__global__ __launch_bounds__(256)
void mfma_gemm1(const float* __restrict__ A, const bf16* __restrict__ Bt,
                const float* __restrict__ bias, bf16* __restrict__ C, int M) {
  __shared__ bf16 As[64][40];
  __shared__ bf16 Bs[256][40];
  const int tid  = threadIdx.x;
  const int lane = tid & 63;
  const int wave = tid >> 6;       // n-quarter (64 cols each)
  const int row0 = blockIdx.x * 64;
  const int l15  = lane & 15;
  const int quad = lane >> 4;

  f32x4 acc[4][4] = {};

  for (int k0 = 0; k0 < FIN; k0 += 32) {
#pragma unroll
    for (int i = 0; i < 2; ++i) {
      int idx = tid + i * 256;          // 0..511
      int r = idx >> 3, c4 = idx & 7;   // row 0..63, float4-col 0..7
      int gr = row0 + r;
      float4 v = make_float4(0.f, 0.f, 0.f, 0.f);
      if (gr < M) v = *(const float4*)&A[(size_t)gr * FIN + k0 + c4 * 4];
      bf16x4 b;
      b[0] = (bf16)v.x; b[1] = (bf16)v.y; b[2] = (bf16)v.z; b[3] = (bf16)v.w;
      *(bf16x4*)&As[r][c4 * 4] = b;
    }
#pragma unroll
    for (int i = 0; i < 4; ++i) {
      int idx = tid + i * 256;           // 0..1023
      int nrow = idx >> 2, k16 = idx & 3;
      bf16x8 v = *(const bf16x8*)&Bt[(size_t)nrow * FIN + k0 + k16 * 8];
      *(bf16x8*)&Bs[nrow][k16 * 8] = v;
    }
    __syncthreads();

    bf16x8 af[4], bfr[4];
#pragma unroll
    for (int mt = 0; mt < 4; ++mt)
      af[mt] = *(const bf16x8*)&As[mt * 16 + l15][quad * 8];
#pragma unroll
    for (int nt = 0; nt < 4; ++nt)
      bfr[nt] = *(const bf16x8*)&Bs[wave * 64 + nt * 16 + l15][quad * 8];
#pragma unroll
    for (int mt = 0; mt < 4; ++mt)
#pragma unroll
      for (int nt = 0; nt < 4; ++nt)
        acc[mt][nt] = __builtin_amdgcn_mfma_f32_16x16x32_bf16(af[mt], bfr[nt],
                                                              acc[mt][nt], 0, 0, 0);
    __syncthreads();
  }

#pragma unroll
  for (int nt = 0; nt < 4; ++nt) {
    int gc = wave * 64 + nt * 16 + l15;
    float bv = bias[gc];
#pragma unroll
    for (int mt = 0; mt < 4; ++mt)
#pragma unroll
      for (int r = 0; r < 4; ++r) {
        int gr = row0 + mt * 16 + quad * 4 + r;
        if (gr < M) {
          float v = fmaxf(acc[mt][nt][r] + bv, 0.f);
          C[(size_t)gr * HID + gc] = (bf16)v;
        }
      }
  }
}

// ---------------- GEMM2: g0 = norm .* (h1 @ w2t^T + b2), BM=128 BN=64 ----------------
__global__ __launch_bounds__(256)
void mfma_gemm2(const bf16* __restrict__ A, const bf16* __restrict__ Bt,
                const float* __restrict__ bias, const float* __restrict__ norm,
                bf16* __restrict__ g0, int M) {
  __shared__ bf16 As[128][40];
  __shared__ bf16 Bs[64][40];
  const int tid  = threadIdx.x;
  const int lane = tid & 63;
  const int wave = tid >> 6;
  const int wm = wave >> 1;
  const int wn = wave & 1;
  const int row0 = blockIdx.x * 128;
  const int l15  = lane & 15;
  const int quad = lane >> 4;

  f32x4 acc[4][2] = {};

  for (int k0 = 0; k0 < HID; k0 += 32) {
#pragma unroll
    for (int i = 0; i < 2; ++i) {
      int idx = tid + i * 256;
      int r = idx >> 2, k16 = idx & 3;
      int gr = row0 + r;
      bf16x8 v = {};
      if (gr < M) v = *(const bf16x8*)&A[(size_t)gr * HID + k0 + k16 * 8];
      *(bf16x8*)&As[r][k16 * 8] = v;
    }
    {
      int nrow = tid >> 2, k16 = tid & 3;
      bf16x8 v = *(const bf16x8*)&Bt[(size_t)nrow * HID + k0 + k16 * 8];
      *(bf16x8*)&Bs[nrow][k16 * 8] = v;
    }
    __syncthreads();

    bf16x8 af[4], bfr[2];
#pragma unroll
    for (int mt = 0; mt < 4; ++mt)
      af[mt] = *(const bf16x8*)&As[wm * 64 + mt * 16 + l15][quad * 8];
#pragma unroll
    for (int nt = 0; nt < 2; ++nt)
      bfr[nt] = *(const bf16x8*)&Bs[wn * 32 + nt * 16 + l15][quad * 8];
#pragma unroll
    for (int mt = 0; mt < 4; ++mt)
#pragma unroll
      for (int nt = 0; nt < 2; ++nt)
        acc[mt][nt] = __builtin_amdgcn_mfma_f32_16x16x32_bf16(af[mt], bfr[nt],
                                                              acc[mt][nt], 0, 0, 0);
    __syncthreads();
  }

#pragma unroll
  for (int nt = 0; nt < 2; ++nt) {
    int gc = wn * 32 + nt * 16 + l15;
    float bv = bias[gc];
#pragma unroll
    for (int mt = 0; mt < 4; ++mt)
#pragma unroll
      for (int r = 0; r < 4; ++r) {
        int gr = row0 + wm * 64 + mt * 16 + quad * 4 + r;
        if (gr < M) {
          float v = acc[mt][nt][r] + bv;
          g0[(size_t)gr * NCLS + gc] = (bf16)(norm[gr] * v);
        }
      }
  }
}

// ---------------- CSR build: bucketed two-pass ----------------
__global__ __launch_bounds__(256)
void bucket_pass1(const int* __restrict__ src, const int* __restrict__ dst,
                  unsigned* __restrict__ bcnt, unsigned* __restrict__ bdata, int E) {
  int e = blockIdx.x * 256 + threadIdx.x;
  if (e >= E) return;
  int s = src[e], d = dst[e];
  int b = d >> 6;
  unsigned p = atomicAdd(&bcnt[b * 16], 1u);
  bdata[(size_t)b * BCAP + p] = ((unsigned)s << 6) | (unsigned)(d & 63);
}

// Pass 2: LDS histogram, wave scan, one global atomic per bucket, local scatter.
// Emits norm (for GEMM2), rnorm (for softmax), norm2a = (1-a)/(deg+1), start/end.
__global__ __launch_bounds__(256)
void bucket_pass2(const unsigned* __restrict__ bcnt, const unsigned* __restrict__ bdata,
                  unsigned* __restrict__ counter, float* __restrict__ norm,
                  float* __restrict__ rnorm, float* __restrict__ norm2a,
                  unsigned* __restrict__ startp, unsigned* __restrict__ endp,
                  int* __restrict__ col) {
  __shared__ unsigned lcnt[64];
  __shared__ unsigned lcur[64];
  const int b = blockIdx.x;
  const int tid = threadIdx.x;
  const unsigned cnt = bcnt[b * 16];
  const unsigned* data = &bdata[(size_t)b * BCAP];

  if (tid < 64) lcnt[tid] = 0;
  __syncthreads();
  for (unsigned i = tid; i < cnt; i += 256)
    atomicAdd(&lcnt[data[i] & 63], 1u);
  __syncthreads();

  if (tid < 64) {
    unsigned v = lcnt[tid];
    unsigned inc = v;
#pragma unroll
    for (int o = 1; o < 64; o <<= 1) {
      unsigned t = __shfl_up(inc, o, 64);
      if (tid >= o) inc += t;
    }
    unsigned base = 0;
    if (tid == 63) base = atomicAdd(counter, inc);
    base = __shfl(base, 63, 64);
    unsigned st = base + inc - v;
    lcur[tid] = st;
    int g = b * 64 + tid;
    if (g < NNODES) {
      startp[g] = st;
      endp[g]   = st + v;
      float dp1 = (float)(v + 1u);
      norm[g]   = rsqrtf(dp1);
      rnorm[g]  = sqrtf(dp1);
      norm2a[g] = (1.0f - ALPHA) / dp1;
    }
  }
  __syncthreads();
  for (unsigned i = tid; i < cnt; i += 256) {
    unsigned v = data[i];
    unsigned p = atomicAdd(&lcur[v & 63], 1u);
    col[p] = (int)(v >> 6);
  }
}

// ---------------- pull propagation on scaled state g = norm.*h ----------------
// g_new = norm2a * (sum_src g[src] + g[self]) + ALPHA * g0
__global__ __launch_bounds__(256)
void appnp_pull_g(const bf16* __restrict__ g, const bf16* __restrict__ g0,
                  const float* __restrict__ norm2a,
                  const unsigned* __restrict__ start, const unsigned* __restrict__ endp,
                  const int* __restrict__ col, bf16* __restrict__ g_new) {
  int wid = (blockIdx.x * 256 + threadIdx.x) >> 6;
  int lane = threadIdx.x & 63;
  if (wid >= NNODES) return;
  unsigned j = start[wid];
  const unsigned j1 = endp[wid];
  float acc = 0.f;
  for (; j + 8 <= j1; j += 8) {
    int i0 = col[j], i1 = col[j + 1], i2 = col[j + 2], i3 = col[j + 3];
    int i4 = col[j + 4], i5 = col[j + 5], i6 = col[j + 6], i7 = col[j + 7];
    float v0 = (float)g[(size_t)i0 * NCLS + lane];
    float v1 = (float)g[(size_t)i1 * NCLS + lane];
    float v2 = (float)g[(size_t)i2 * NCLS + lane];
    float v3 = (float)g[(size_t)i3 * NCLS + lane];
    float v4 = (float)g[(size_t)i4 * NCLS + lane];
    float v5 = (float)g[(size_t)i5 * NCLS + lane];
    float v6 = (float)g[(size_t)i6 * NCLS + lane];
    float v7 = (float)g[(size_t)i7 * NCLS + lane];
    acc += ((v0 + v1) + (v2 + v3)) + ((v4 + v5) + (v6 + v7));
  }
  for (; j < j1; ++j)
    acc += (float)g[(size_t)col[j] * NCLS + lane];
  size_t idx = (size_t)wid * NCLS + lane;
  acc += (float)g[idx];                               // self-loop
  g_new[idx] = (bf16)fmaf(norm2a[wid], acc, ALPHA * (float)g0[idx]);
}

// ---------------- log_softmax on h = g .* rnorm ----------------
__global__ __launch_bounds__(256)
void log_softmax_k(const bf16* __restrict__ g, const float* __restrict__ rnorm,
                   float* __restrict__ out, int n) {
  int wave = threadIdx.x >> 6;
  int lane = threadIdx.x & 63;
  int row = blockIdx.x * 4 + wave;
  if (row >= n) return;
  float x = (float)g[(size_t)row * NCLS + lane] * rnorm[row];
  float m = x;
#pragma unroll
  for (int o = 32; o; o >>= 1) m = fmaxf(m, __shfl_xor(m, o, 64));
  float ex = expf(x - m);
  float s = ex;
#pragma unroll
  for (int o = 32; o; o >>= 1) s += __shfl_xor(s, o, 64);
  out[(size_t)row * NCLS + lane] = x - m - logf(s);
}

// ---------------- launch ----------------
extern "C" void kernel_launch(void* const* d_in, const int* in_sizes, int n_in,
                              void* d_out, int out_size, void* d_ws, size_t ws_size,
                              hipStream_t stream) {
  (void)n_in; (void)out_size; (void)ws_size;
  const float* feat = (const float*)d_in[0];
  const float* w1   = (const float*)d_in[1];
  const float* b1   = (const float*)d_in[2];
  const float* w2   = (const float*)d_in[3];
  const float* b2   = (const float*)d_in[4];
  const int*   src  = (const int*)d_in[5];
  const int*   dst  = (const int*)d_in[6];
  const int E = in_sizes[5];
  float* out = (float*)d_out;

  // workspace layout (~99 MB)
  char* ws = (char*)d_ws;
  size_t off = 0;
  float* norm   = (float*)(ws + off);         off += ((size_t)NNODES * 4 + 255) & ~(size_t)255;
  float* rnorm  = (float*)(ws + off);         off += ((size_t)NNODES * 4 + 255) & ~(size_t)255;
  float* norm2a = (float*)(ws + off);         off += ((size_t)NNODES * 4 + 255) & ~(size_t)255;
  unsigned* startp = (unsigned*)(ws + off);   off += ((size_t)NNODES * 4 + 255) & ~(size_t)255;
  unsigned* endp   = (unsigned*)(ws + off);   off += ((size_t)NNODES * 4 + 255) & ~(size_t)255;
  unsigned* counter = (unsigned*)(ws + off);  off += 256;
  bf16* g0 = (bf16*)(ws + off);               off += (size_t)NNODES * NCLS * 2;   // 12.8 MB
  // X region (51.2 MB): h1b [N][HID] bf16 during MLP; pb0/pb1 alias it (written
  // only after GEMM2 consumed h1b).
  char* X = ws + off;                         off += (size_t)NNODES * HID * 2;
  bf16* h1b = (bf16*)X;
  bf16* pb0 = (bf16*)X;
  bf16* pb1 = (bf16*)(X + (size_t)NNODES * NCLS * 2);
  int*  col = (int*)(ws + off);               off += ((size_t)E * 4 + 255) & ~(size_t)255;  // 12.8 MB
  unsigned* bcnt  = (unsigned*)(ws + off);    off += ((size_t)NBUCK * 16 * 4 + 255) & ~(size_t)255;
  unsigned* bdata = (unsigned*)(ws + off);    off += (size_t)NBUCK * BCAP * 4;     // 19.2 MB
  bf16* w1t = (bf16*)(ws + off);              off += ((size_t)HID * FIN * 2 + 255) & ~(size_t)255;
  bf16* w2t = (bf16*)(ws + off);              off += ((size_t)NCLS * HID * 2 + 255) & ~(size_t)255;

  // ---- CSR pass 1 ----
  hipMemsetAsync(bcnt, 0, (size_t)NBUCK * 16 * 4, stream);
  hipMemsetAsync(counter, 0, 256, stream);
  bucket_pass1<<<(E + 255) / 256, 256, 0, stream>>>(src, dst, bcnt, bdata, E);

  // ---- weight transpose/convert (tiny) ----
  transpose_bf16<<<(FIN * HID + 255) / 256, 256, 0, stream>>>(w1, w1t, FIN, HID);
  transpose_bf16<<<(HID * NCLS + 255) / 256, 256, 0, stream>>>(w2, w2t, HID, NCLS);

  // ---- GEMM1 (A fetched once) ----
  mfma_gemm1<<<(NNODES + 63) / 64, 256, 0, stream>>>(feat, w1t, b1, h1b, NNODES);

  // ---- CSR pass 2 (norm needed by GEMM2 epilogue) ----
  bucket_pass2<<<NBUCK, 256, 0, stream>>>(bcnt, bdata, counter, norm, rnorm,
                                          norm2a, startp, endp, col);

  // ---- GEMM2 with fused norm-scaling: writes g0 = norm .* h0 ----
  mfma_gemm2<<<(NNODES + 127) / 128, 256, 0, stream>>>(h1b, w2t, b2, norm, g0, NNODES);

  // ---- APPNP propagation on scaled state ----
  const bf16* cur = g0;
  bf16* bufs[2] = {pb0, pb1};
  const int nblocks = (NNODES * 64 + 255) / 256;
  for (int k = 0; k < KSTEPS; ++k) {
    bf16* nxt = bufs[k & 1];
    appnp_pull_g<<<nblocks, 256, 0, stream>>>(cur, g0, norm2a, startp, endp, col, nxt);
    cur = nxt;
  }

  // ---- log_softmax (unscale by rnorm) ----
  log_softmax_k<<<(NNODES + 3) / 4, 256, 0, stream>>>(cur, rnorm, out, NNODES);
}